// Round 1
// baseline (692.018 us; speedup 1.0000x reference)
//
#include <hip/hip_runtime.h>

// Problem constants (from reference): B=32, T=400, P=10000, N = T*P = 4e6.
#define BATCH 32
#define NELEM 4000000
#define N4 (NELEM / 4)      // 1,000,000 float4 per batch row
#define BLK 256
#define GRID_X 128          // 128 blocks per batch row -> 4096 blocks total

__global__ void init_out_kernel(float* __restrict__ out,
                                const float* __restrict__ fc1_b) {
    int i = threadIdx.x;
    if (i < BATCH) out[i] = fc1_b[0];
}

__global__ __launch_bounds__(BLK)
void fused_dot_kernel(const float4* __restrict__ x,    // [BATCH][N4]
                      const float4* __restrict__ W,    // [N4]
                      const float4* __restrict__ f,    // [N4]
                      float* __restrict__ out) {       // [BATCH]
    const int b = blockIdx.y;
    const float4* __restrict__ xb = x + (size_t)b * N4;

    float acc = 0.0f;
    const int stride = gridDim.x * blockDim.x;
    for (int i = blockIdx.x * blockDim.x + threadIdx.x; i < N4; i += stride) {
        float4 xv = xb[i];
        float4 wv = W[i];
        float4 fv = f[i];
        acc += xv.x * fabsf(wv.x) * fv.x;
        acc += xv.y * fabsf(wv.y) * fv.y;
        acc += xv.z * fabsf(wv.z) * fv.z;
        acc += xv.w * fabsf(wv.w) * fv.w;
    }

    // Wave-64 shuffle reduction
    #pragma unroll
    for (int off = 32; off > 0; off >>= 1)
        acc += __shfl_down(acc, off, 64);

    __shared__ float s[BLK / 64];
    const int lane = threadIdx.x & 63;
    const int wave = threadIdx.x >> 6;
    if (lane == 0) s[wave] = acc;
    __syncthreads();

    if (threadIdx.x == 0) {
        float t = 0.0f;
        #pragma unroll
        for (int w = 0; w < BLK / 64; ++w) t += s[w];
        atomicAdd(&out[b], t);
    }
}

extern "C" void kernel_launch(void* const* d_in, const int* in_sizes, int n_in,
                              void* d_out, int out_size, void* d_ws, size_t ws_size,
                              hipStream_t stream) {
    const float* x     = (const float*)d_in[0];  // [B, T, P]
    const float* W     = (const float*)d_in[1];  // [T, P]
    const float* fc1_w = (const float*)d_in[2];  // [1, T*P]
    const float* fc1_b = (const float*)d_in[3];  // [1]
    float* out = (float*)d_out;                  // [B, 1]

    // out is re-poisoned before every call: initialize with bias each time.
    init_out_kernel<<<1, 64, 0, stream>>>(out, fc1_b);

    dim3 grid(GRID_X, BATCH);
    fused_dot_kernel<<<grid, BLK, 0, stream>>>(
        (const float4*)x, (const float4*)W, (const float4*)fc1_w, out);
}

// Round 2
// 668.984 us; speedup vs baseline: 1.0344x; 1.0344x over previous
//
#include <hip/hip_runtime.h>

// out[b] = sum_{i} x[b,i] * |W[i]| * fc1_w[i] + fc1_b ; B=32, N = T*P = 4e6.
// Strategy: each (block.x, group) computes s = |W|*fc1_w once in registers and
// reuses it for 8 batch rows -> every input byte crosses HBM exactly once
// (~544 MB total => ~86 us floor at 6.3 TB/s).
#define BATCH 32
#define NELEM 4000000
#define N4 (NELEM / 4)     // 1,000,000 float4 per batch row
#define BLK 256
#define BPG 8              // batch rows per group
#define GROUPS (BATCH / BPG)
#define NBLK 512           // blocks per group -> 2048 blocks total (8/CU)

__global__ __launch_bounds__(BLK)
void stage1_kernel(const float4* __restrict__ x,   // [BATCH][N4]
                   const float4* __restrict__ W,   // [N4]
                   const float4* __restrict__ F,   // [N4]
                   float* __restrict__ partials) { // [BATCH][NBLK]
    const int g  = blockIdx.y;                     // batch group 0..GROUPS-1
    const int bx = blockIdx.x;                     // 0..NBLK-1
    const float4* __restrict__ xg = x + (size_t)g * BPG * N4;

    float acc[BPG];
    #pragma unroll
    for (int r = 0; r < BPG; ++r) acc[r] = 0.0f;

    const int stride = NBLK * BLK;
    for (int i = bx * BLK + threadIdx.x; i < N4; i += stride) {
        float4 wv = W[i];
        float4 fv = F[i];
        float4 s;
        s.x = fabsf(wv.x) * fv.x;
        s.y = fabsf(wv.y) * fv.y;
        s.z = fabsf(wv.z) * fv.z;
        s.w = fabsf(wv.w) * fv.w;
        const float4* __restrict__ xp = xg + i;
        #pragma unroll
        for (int r = 0; r < BPG; ++r) {
            float4 xv = xp[(size_t)r * N4];
            acc[r] += xv.x * s.x + xv.y * s.y + xv.z * s.z + xv.w * s.w;
        }
    }

    // Wave-64 shuffle reduction for each of the 8 accumulators.
    #pragma unroll
    for (int r = 0; r < BPG; ++r) {
        #pragma unroll
        for (int off = 32; off > 0; off >>= 1)
            acc[r] += __shfl_down(acc[r], off, 64);
    }

    __shared__ float lds[BLK / 64][BPG];
    const int lane = threadIdx.x & 63;
    const int wv   = threadIdx.x >> 6;
    if (lane == 0) {
        #pragma unroll
        for (int r = 0; r < BPG; ++r) lds[wv][r] = acc[r];
    }
    __syncthreads();

    if (threadIdx.x < BPG) {
        const int r = threadIdx.x;
        float t = lds[0][r] + lds[1][r] + lds[2][r] + lds[3][r];
        partials[(size_t)(g * BPG + r) * NBLK + bx] = t;
    }
}

__global__ __launch_bounds__(64)
void stage2_kernel(const float* __restrict__ partials, // [BATCH][NBLK]
                   const float* __restrict__ fc1_b,
                   float* __restrict__ out) {          // [BATCH]
    const int b    = blockIdx.x;   // 0..BATCH-1
    const int lane = threadIdx.x;  // 0..63
    float t = 0.0f;
    #pragma unroll
    for (int k = lane; k < NBLK; k += 64) t += partials[(size_t)b * NBLK + k];
    #pragma unroll
    for (int off = 32; off > 0; off >>= 1) t += __shfl_down(t, off, 64);
    if (lane == 0) out[b] = t + fc1_b[0];
}

extern "C" void kernel_launch(void* const* d_in, const int* in_sizes, int n_in,
                              void* d_out, int out_size, void* d_ws, size_t ws_size,
                              hipStream_t stream) {
    const float* x     = (const float*)d_in[0];  // [B, T, P]
    const float* W     = (const float*)d_in[1];  // [T, P]
    const float* fc1_w = (const float*)d_in[2];  // [1, T*P]
    const float* fc1_b = (const float*)d_in[3];  // [1]
    float* out      = (float*)d_out;             // [B, 1]
    float* partials = (float*)d_ws;              // BATCH*NBLK floats (64 KB)

    dim3 grid(NBLK, GROUPS);
    stage1_kernel<<<grid, BLK, 0, stream>>>(
        (const float4*)x, (const float4*)W, (const float4*)fc1_w, partials);
    stage2_kernel<<<BATCH, 64, 0, stream>>>(partials, fc1_b, out);
}